// Round 6
// baseline (276.853 us; speedup 1.0000x reference)
//
#include <hip/hip_runtime.h>
#include <stdint.h>

// Problem constants (match reference)
constexpr int B = 1024, N = 100, C = 256, K = 3;
constexpr int ROWS = B * N;                        // 102400
constexpr int THREADS = 256;                        // 4 waves
constexpr int STEP_ROWS = 8;                        // rows staged per pipeline step
constexpr int BLOCKS = 1280;                        // 5 blocks/CU (LDS-limited)
constexpr int ROWS_PER_BLOCK = ROWS / BLOCKS;       // 80, exact
constexpr int NSTEPS = ROWS_PER_BLOCK / STEP_ROWS;  // 10, exact
constexpr float LN_EPS = 1e-5f;

// 64-lane butterfly sum: all lanes end with the total. (Proven round 0.)
__device__ __forceinline__ float wavesum(float x) {
    #pragma unroll
    for (int off = 32; off > 0; off >>= 1) x += __shfl_xor(x, off);
    return x;
}

__global__ __launch_bounds__(256) void dydwconv_ln_kernel(
    const float* __restrict__ query,   // [B,N,C]
    const float* __restrict__ value,   // [B,N,C]
    const float* __restrict__ Ww,      // [K,C]
    const float* __restrict__ bw,      // [K]
    const float* __restrict__ gamma,   // [C]
    const float* __restrict__ beta,    // [C]
    float* __restrict__ out)           // [B,N,C]
{
    // Double-buffered staging: [2][ 8 rows of q | 8 rows of v ] = 32 KB.
    // Layout must be LINEAR (global_load_lds writes base + lane*16).
    __shared__ float sbuf[2][STEP_ROWS * 2 * C];

    const int t    = threadIdx.x;
    const int lane = t & 63;
    const int wave = t >> 6;
    const int c0   = lane * 4;
    const int rowBase = blockIdx.x * ROWS_PER_BLOCK;   // 80 contiguous rows

    // Per-lane constants in registers (L1-hot, loaded once per block-life).
    const float4 Wa = *(const float4*)(Ww + c0);
    const float4 Wb = *(const float4*)(Ww + C + c0);
    const float4 Wc = *(const float4*)(Ww + 2 * C + c0);
    const float4 g4 = *(const float4*)(gamma + c0);
    const float4 b4 = *(const float4*)(beta + c0);
    const float  b0 = bw[0], b1 = bw[1], b2 = bw[2];

    // ---- async stage of one 8-row step into LDS buffer `buf` ----
    // 16 segments of 1 KB (8 rows x {q,v}); wave w issues segments 4w..4w+3.
    // Zero VGPR cost; tracked by vmcnt -> the register allocator cannot
    // serialize it (this is the lever rounds 4-5 failed to pull).
    auto stage = [&](int buf, int step) {
        const int r0 = rowBase + step * STEP_ROWS;
        #pragma unroll
        for (int k2 = 0; k2 < 4; ++k2) {
            const int idx = wave * 4 + k2;          // 0..15, wave-uniform
            const int r   = idx & 7;
            const float* gsrc = ((idx < 8) ? query : value)
                              + (size_t)(r0 + r) * C + lane * 4;  // per-lane 16B
            float* ldst = &sbuf[buf][idx * C];       // wave-uniform base
            __builtin_amdgcn_global_load_lds(
                (const __attribute__((address_space(1))) uint32_t*)gsrc,
                (__attribute__((address_space(3))) uint32_t*)ldst,
                16, 0, 0);
        }
    };

    // ---- compute one staged step from LDS (wave handles 2 rows) ----
    auto compute = [&](int buf, int step) {
        const int r0 = rowBase + step * STEP_ROWS;
        #pragma unroll
        for (int rr = 0; rr < 2; ++rr) {
            const int r = wave * 2 + rr;             // 0..7 within step
            const float4 q = *(const float4*)(&sbuf[buf][r * C] + c0);
            const float4 v = *(const float4*)(&sbuf[buf][(STEP_ROWS + r) * C] + c0);

            // dynamic kernel taps
            float p0 = q.x * Wa.x + q.y * Wa.y + q.z * Wa.z + q.w * Wa.w;
            float p1 = q.x * Wb.x + q.y * Wb.y + q.z * Wb.z + q.w * Wb.w;
            float p2 = q.x * Wc.x + q.y * Wc.y + q.z * Wc.z + q.w * Wc.w;
            const float w0 = wavesum(p0) + b0;
            const float w1 = wavesum(p1) + b1;
            const float w2 = wavesum(p2) + b2;

            // K=3 depthwise conv along channels (zero-padded)
            float vl = __shfl_up(v.w, 1);
            float vr = __shfl_down(v.x, 1);
            if (lane == 0)  vl = 0.0f;
            if (lane == 63) vr = 0.0f;
            const float o0 = vl  * w0 + v.x * w1 + v.y * w2;
            const float o1 = v.x * w0 + v.y * w1 + v.z * w2;
            const float o2 = v.y * w0 + v.z * w1 + v.w * w2;
            const float o3 = v.z * w0 + v.w * w1 + vr  * w2;

            // LayerNorm over C
            float s  = (o0 + o1) + (o2 + o3);
            float ss = o0 * o0 + o1 * o1 + o2 * o2 + o3 * o3;
            s  = wavesum(s);
            ss = wavesum(ss);
            const float mu  = s * (1.0f / C);
            const float var = ss * (1.0f / C) - mu * mu;
            const float inv = rsqrtf(var + LN_EPS);

            float4 res;
            res.x = (o0 - mu) * inv * g4.x + b4.x;
            res.y = (o1 - mu) * inv * g4.y + b4.y;
            res.z = (o2 - mu) * inv * g4.z + b4.z;
            res.w = (o3 - mu) * inv * g4.w + b4.w;
            *(float4*)(out + (size_t)(r0 + r) * C + c0) = res;
        }
    };

    // ---- 2-phase pipeline (T3 minimal recipe) ----
    stage(0, 0);
    __syncthreads();                  // drain: buf0 ready
    int cur = 0;
    for (int stp = 0; stp < NSTEPS - 1; ++stp) {
        stage(cur ^ 1, stp + 1);      // issue next step's 16 KB FIRST
        compute(cur, stp);            // overlaps with the staging flight
        __syncthreads();              // stage done + all waves finished buf
        cur ^= 1;
    }
    compute(cur, NSTEPS - 1);         // epilogue
}

extern "C" void kernel_launch(void* const* d_in, const int* in_sizes, int n_in,
                              void* d_out, int out_size, void* d_ws, size_t ws_size,
                              hipStream_t stream) {
    const float* query = (const float*)d_in[0];
    const float* value = (const float*)d_in[1];
    const float* Ww    = (const float*)d_in[2];
    const float* bw    = (const float*)d_in[3];
    const float* gamma = (const float*)d_in[4];
    const float* beta  = (const float*)d_in[5];
    float* outp = (float*)d_out;

    dydwconv_ln_kernel<<<BLOCKS, THREADS, 0, stream>>>(
        query, value, Ww, bw, gamma, beta, outp);
}

// Round 7
// 261.835 us; speedup vs baseline: 1.0574x; 1.0574x over previous
//
#include <hip/hip_runtime.h>

// Problem constants (match reference)
constexpr int B = 1024, N = 100, C = 256, K = 3;
constexpr int ROWS = B * N;                        // 102400
constexpr int THREADS = 256;
constexpr int WAVES_PER_BLOCK = 4;
constexpr int RPW = 5;                             // rows per wave, all in flight
constexpr int ROWS_PER_BLOCK = WAVES_PER_BLOCK * RPW;   // 20
constexpr int BLOCKS = ROWS / ROWS_PER_BLOCK;      // 5120, exact
constexpr float LN_EPS = 1e-5f;

typedef float f32x4 __attribute__((ext_vector_type(4)));

// 64-lane butterfly sum: all lanes end with the total. (Proven round 0.)
__device__ __forceinline__ float wavesum(float x) {
    #pragma unroll
    for (int off = 32; off > 0; off >>= 1) x += __shfl_xor(x, off);
    return x;
}

__global__ __launch_bounds__(256, 4) void dydwconv_ln_kernel(
    const float* __restrict__ query,   // [B,N,C]
    const float* __restrict__ value,   // [B,N,C]
    const float* __restrict__ Ww,      // [K,C]
    const float* __restrict__ bw,      // [K]
    const float* __restrict__ gamma,   // [C]
    const float* __restrict__ beta,    // [C]
    float* __restrict__ out)           // [B,N,C]
{
    const int t    = threadIdx.x;
    const int lane = t & 63;
    const int c0   = lane * 4;
    const int wave = t >> 6;
    const int r0   = (blockIdx.x * WAVES_PER_BLOCK + wave) * RPW;  // 5 consecutive rows
    const size_t base0 = (size_t)r0 * C + c0;

    // ---- Issue ALL 10 row loads back-to-back: 10 KB in flight per wave ----
    f32x4 q[RPW], v[RPW];
    #pragma unroll
    for (int i = 0; i < RPW; ++i) {
        q[i] = *(const f32x4*)(query + base0 + (size_t)i * C);
        v[i] = *(const f32x4*)(value + base0 + (size_t)i * C);
    }
    // HARD FENCE: every loaded vector must be materialized in VGPRs here.
    // This is what rounds 4/5 were missing — the register allocator had
    // sunk/serialized the loads (VGPR_Count 28/32 proved it). "+v" makes
    // sinking illegal; sched_barrier stops the machine scheduler too.
    #pragma unroll
    for (int i = 0; i < RPW; ++i) {
        asm volatile("" : "+v"(q[i]));
        asm volatile("" : "+v"(v[i]));
    }
    __builtin_amdgcn_sched_barrier(0);

    // Per-lane constants (L1-hot; loaded under the big-load shadow is fine).
    const f32x4 Wa = *(const f32x4*)(Ww + c0);
    const f32x4 Wb = *(const f32x4*)(Ww + C + c0);
    const f32x4 Wc = *(const f32x4*)(Ww + 2 * C + c0);
    const f32x4 g4 = *(const f32x4*)(gamma + c0);
    const f32x4 b4 = *(const f32x4*)(beta + c0);
    const float b0 = bw[0], b1 = bw[1], b2 = bw[2];

    // ---- Phase A: tap partials (drains q[i] in arrival order) ----
    float p0[RPW], p1[RPW], p2[RPW];
    #pragma unroll
    for (int i = 0; i < RPW; ++i) {
        p0[i] = q[i][0] * Wa[0] + q[i][1] * Wa[1] + q[i][2] * Wa[2] + q[i][3] * Wa[3];
        p1[i] = q[i][0] * Wb[0] + q[i][1] * Wb[1] + q[i][2] * Wb[2] + q[i][3] * Wb[3];
        p2[i] = q[i][0] * Wc[0] + q[i][1] * Wc[1] + q[i][2] * Wc[2] + q[i][3] * Wc[3];
    }

    // ---- Phase B: 15 independent 6-stage reduce chains, interleaved ----
    float w0[RPW], w1[RPW], w2[RPW];
    #pragma unroll
    for (int i = 0; i < RPW; ++i) {
        w0[i] = wavesum(p0[i]) + b0;
        w1[i] = wavesum(p1[i]) + b1;
        w2[i] = wavesum(p2[i]) + b2;
    }

    // ---- Phase C: K=3 conv (zero-padded) + LN partials ----
    f32x4 o[RPW];
    float s[RPW], ss[RPW];
    #pragma unroll
    for (int i = 0; i < RPW; ++i) {
        float vl = __shfl_up(v[i][3], 1);     // value[c0-1]
        float vr = __shfl_down(v[i][0], 1);   // value[c0+4]
        if (lane == 0)  vl = 0.0f;
        if (lane == 63) vr = 0.0f;
        o[i][0] = vl      * w0[i] + v[i][0] * w1[i] + v[i][1] * w2[i];
        o[i][1] = v[i][0] * w0[i] + v[i][1] * w1[i] + v[i][2] * w2[i];
        o[i][2] = v[i][1] * w0[i] + v[i][2] * w1[i] + v[i][3] * w2[i];
        o[i][3] = v[i][2] * w0[i] + v[i][3] * w1[i] + vr      * w2[i];
        s[i]  = (o[i][0] + o[i][1]) + (o[i][2] + o[i][3]);
        ss[i] = o[i][0] * o[i][0] + o[i][1] * o[i][1]
              + o[i][2] * o[i][2] + o[i][3] * o[i][3];
    }

    // ---- Phase D: 10 independent reduce chains, interleaved ----
    #pragma unroll
    for (int i = 0; i < RPW; ++i) {
        s[i]  = wavesum(s[i]);
        ss[i] = wavesum(ss[i]);
    }

    // ---- Phase E: normalize + store ----
    #pragma unroll
    for (int i = 0; i < RPW; ++i) {
        const float mu  = s[i] * (1.0f / C);
        const float var = ss[i] * (1.0f / C) - mu * mu;
        const float inv = rsqrtf(var + LN_EPS);
        f32x4 r;
        r[0] = (o[i][0] - mu) * inv * g4[0] + b4[0];
        r[1] = (o[i][1] - mu) * inv * g4[1] + b4[1];
        r[2] = (o[i][2] - mu) * inv * g4[2] + b4[2];
        r[3] = (o[i][3] - mu) * inv * g4[3] + b4[3];
        *(f32x4*)(out + base0 + (size_t)i * C) = r;
    }
}

extern "C" void kernel_launch(void* const* d_in, const int* in_sizes, int n_in,
                              void* d_out, int out_size, void* d_ws, size_t ws_size,
                              hipStream_t stream) {
    const float* query = (const float*)d_in[0];
    const float* value = (const float*)d_in[1];
    const float* Ww    = (const float*)d_in[2];
    const float* bw    = (const float*)d_in[3];
    const float* gamma = (const float*)d_in[4];
    const float* beta  = (const float*)d_in[5];
    float* outp = (float*)d_out;

    dydwconv_ln_kernel<<<BLOCKS, THREADS, 0, stream>>>(
        query, value, Ww, bw, gamma, beta, outp);
}

// Round 8
// 244.954 us; speedup vs baseline: 1.1302x; 1.0689x over previous
//
#include <hip/hip_runtime.h>

// Problem constants (match reference)
constexpr int B = 1024, N = 100, C = 256, K = 3;
constexpr int ROWS = B * N;            // 102400
constexpr int WAVES_PER_BLOCK = 4;     // 256 threads / 64-lane waves
constexpr int BLOCKS = ROWS / WAVES_PER_BLOCK;  // 25600, exact
constexpr float LN_EPS = 1e-5f;

typedef float f32x4 __attribute__((ext_vector_type(4)));

__global__ __launch_bounds__(256) void dydwconv_ln_kernel(
    const float* __restrict__ query,   // [B,N,C]
    const float* __restrict__ value,   // [B,N,C]
    const float* __restrict__ Ww,      // [K,C]
    const float* __restrict__ bw,      // [K]
    const float* __restrict__ gamma,   // [C]
    const float* __restrict__ beta,    // [C]
    float* __restrict__ out)           // [B,N,C]
{
    __shared__ float sW[K * C];        // 3 KB
    __shared__ float sGamma[C];
    __shared__ float sBeta[C];
    __shared__ float sBw[K];

    const int t = threadIdx.x;
    // Stage small read-mostly tensors into LDS (once per block)
    sW[t]         = Ww[t];
    sW[t + C]     = Ww[t + C];
    sW[t + 2 * C] = Ww[t + 2 * C];
    sGamma[t] = gamma[t];
    sBeta[t]  = beta[t];
    if (t < K) sBw[t] = bw[t];
    __syncthreads();

    const int wave = t >> 6;
    const int lane = t & 63;
    const int row  = blockIdx.x * WAVES_PER_BLOCK + wave;  // < ROWS always (exact division)

    const size_t base = (size_t)row * C + lane * 4;
    // SINGLE-VARIABLE CHANGE vs the 92us baseline: non-temporal loads for
    // the two streamed inputs (nt bit -> bypass/no-allocate in L3).
    // q+v+out = 300MB vs 256MB L3: the normal-load version thrashes L3
    // (FETCH showed only half the reads reaching HBM); this probe moves
    // the read path to the pure-stream regime of the 6.3 TB/s copy bench.
    const f32x4 q4 = __builtin_nontemporal_load((const f32x4*)(query + base));
    const f32x4 v4 = __builtin_nontemporal_load((const f32x4*)(value + base));

    const int c0 = lane * 4;
    // Partial dots for the 3 dynamic kernel taps
    float p0 = q4[0] * sW[c0]       + q4[1] * sW[c0 + 1]       + q4[2] * sW[c0 + 2]       + q4[3] * sW[c0 + 3];
    float p1 = q4[0] * sW[C + c0]   + q4[1] * sW[C + c0 + 1]   + q4[2] * sW[C + c0 + 2]   + q4[3] * sW[C + c0 + 3];
    float p2 = q4[0] * sW[2*C + c0] + q4[1] * sW[2*C + c0 + 1] + q4[2] * sW[2*C + c0 + 2] + q4[3] * sW[2*C + c0 + 3];

    #pragma unroll
    for (int off = 32; off > 0; off >>= 1) {
        p0 += __shfl_xor(p0, off);
        p1 += __shfl_xor(p1, off);
        p2 += __shfl_xor(p2, off);
    }
    const float w0 = p0 + sBw[0];
    const float w1 = p1 + sBw[1];
    const float w2 = p2 + sBw[2];

    // Halo exchange for the K=3 conv along channels (zero padding at ends)
    float vleft  = __shfl_up(v4[3], 1);    // value[c0-1] (prev lane's .w)
    float vright = __shfl_down(v4[0], 1);  // value[c0+4] (next lane's .x)
    if (lane == 0)  vleft  = 0.0f;
    if (lane == 63) vright = 0.0f;

    // out[c] = v[c-1]*w0 + v[c]*w1 + v[c+1]*w2  (cross-correlation, pad=1)
    const float o0 = vleft * w0 + v4[0] * w1 + v4[1] * w2;
    const float o1 = v4[0] * w0 + v4[1] * w1 + v4[2] * w2;
    const float o2 = v4[1] * w0 + v4[2] * w1 + v4[3] * w2;
    const float o3 = v4[2] * w0 + v4[3] * w1 + vright * w2;

    // LayerNorm over C
    float s  = o0 + o1 + o2 + o3;
    float ss = o0 * o0 + o1 * o1 + o2 * o2 + o3 * o3;
    #pragma unroll
    for (int off = 32; off > 0; off >>= 1) {
        s  += __shfl_xor(s, off);
        ss += __shfl_xor(ss, off);
    }
    const float mu  = s * (1.0f / C);
    const float var = ss * (1.0f / C) - mu * mu;
    const float inv = rsqrtf(var + LN_EPS);

    float4 r;
    r.x = (o0 - mu) * inv * sGamma[c0]     + sBeta[c0];
    r.y = (o1 - mu) * inv * sGamma[c0 + 1] + sBeta[c0 + 1];
    r.z = (o2 - mu) * inv * sGamma[c0 + 2] + sBeta[c0 + 2];
    r.w = (o3 - mu) * inv * sGamma[c0 + 3] + sBeta[c0 + 3];
    // Plain (cached) stores — the fastest rounds all used plain stores.
    *(float4*)(out + base) = r;
}

extern "C" void kernel_launch(void* const* d_in, const int* in_sizes, int n_in,
                              void* d_out, int out_size, void* d_ws, size_t ws_size,
                              hipStream_t stream) {
    const float* query = (const float*)d_in[0];
    const float* value = (const float*)d_in[1];
    const float* Ww    = (const float*)d_in[2];
    const float* bw    = (const float*)d_in[3];
    const float* gamma = (const float*)d_in[4];
    const float* beta  = (const float*)d_in[5];
    float* outp = (float*)d_out;

    dydwconv_ln_kernel<<<BLOCKS, 256, 0, stream>>>(
        query, value, Ww, bw, gamma, beta, outp);
}

// Round 9
// 244.182 us; speedup vs baseline: 1.1338x; 1.0032x over previous
//
#include <hip/hip_runtime.h>

// Problem constants (match reference)
constexpr int B = 1024, N = 100, C = 256, K = 3;
constexpr int ROWS = B * N;            // 102400
constexpr int WAVES_PER_BLOCK = 4;     // 256 threads / 64-lane waves
constexpr int BLOCKS = ROWS / WAVES_PER_BLOCK;  // 25600, exact
constexpr float LN_EPS = 1e-5f;

typedef float f32x4 __attribute__((ext_vector_type(4)));

__global__ __launch_bounds__(256) void dydwconv_ln_kernel(
    const float* __restrict__ query,   // [B,N,C]
    const float* __restrict__ value,   // [B,N,C]
    const float* __restrict__ Ww,      // [K,C]
    const float* __restrict__ bw,      // [K]
    const float* __restrict__ gamma,   // [C]
    const float* __restrict__ beta,    // [C]
    float* __restrict__ out)           // [B,N,C]
{
    __shared__ float sW[K * C];        // 3 KB
    __shared__ float sGamma[C];
    __shared__ float sBeta[C];
    __shared__ float sBw[K];

    const int t = threadIdx.x;
    // Stage small read-mostly tensors into LDS (once per block)
    sW[t]         = Ww[t];
    sW[t + C]     = Ww[t + C];
    sW[t + 2 * C] = Ww[t + 2 * C];
    sGamma[t] = gamma[t];
    sBeta[t]  = beta[t];
    if (t < K) sBw[t] = bw[t];
    __syncthreads();

    const int wave = t >> 6;
    const int lane = t & 63;
    const int row  = blockIdx.x * WAVES_PER_BLOCK + wave;  // < ROWS always (exact division)

    const size_t base = (size_t)row * C + lane * 4;
    // Non-temporal loads (round-8 win, 92->64us): q+v+out = 300MB > 256MB L3;
    // nt suppresses read-side L3 allocation churn while still getting hits.
    const f32x4 q4 = __builtin_nontemporal_load((const f32x4*)(query + base));
    const f32x4 v4 = __builtin_nontemporal_load((const f32x4*)(value + base));

    const int c0 = lane * 4;
    // Partial dots for the 3 dynamic kernel taps
    float p0 = q4[0] * sW[c0]       + q4[1] * sW[c0 + 1]       + q4[2] * sW[c0 + 2]       + q4[3] * sW[c0 + 3];
    float p1 = q4[0] * sW[C + c0]   + q4[1] * sW[C + c0 + 1]   + q4[2] * sW[C + c0 + 2]   + q4[3] * sW[C + c0 + 3];
    float p2 = q4[0] * sW[2*C + c0] + q4[1] * sW[2*C + c0 + 1] + q4[2] * sW[2*C + c0 + 2] + q4[3] * sW[2*C + c0 + 3];

    #pragma unroll
    for (int off = 32; off > 0; off >>= 1) {
        p0 += __shfl_xor(p0, off);
        p1 += __shfl_xor(p1, off);
        p2 += __shfl_xor(p2, off);
    }
    const float w0 = p0 + sBw[0];
    const float w1 = p1 + sBw[1];
    const float w2 = p2 + sBw[2];

    // Halo exchange for the K=3 conv along channels (zero padding at ends)
    float vleft  = __shfl_up(v4[3], 1);    // value[c0-1] (prev lane's .w)
    float vright = __shfl_down(v4[0], 1);  // value[c0+4] (next lane's .x)
    if (lane == 0)  vleft  = 0.0f;
    if (lane == 63) vright = 0.0f;

    // out[c] = v[c-1]*w0 + v[c]*w1 + v[c+1]*w2  (cross-correlation, pad=1)
    const float o0 = vleft * w0 + v4[0] * w1 + v4[1] * w2;
    const float o1 = v4[0] * w0 + v4[1] * w1 + v4[2] * w2;
    const float o2 = v4[1] * w0 + v4[2] * w1 + v4[3] * w2;
    const float o3 = v4[2] * w0 + v4[3] * w1 + vright * w2;

    // LayerNorm over C
    float s  = o0 + o1 + o2 + o3;
    float ss = o0 * o0 + o1 * o1 + o2 * o2 + o3 * o3;
    #pragma unroll
    for (int off = 32; off > 0; off >>= 1) {
        s  += __shfl_xor(s, off);
        ss += __shfl_xor(ss, off);
    }
    const float mu  = s * (1.0f / C);
    const float var = ss * (1.0f / C) - mu * mu;
    const float inv = rsqrtf(var + LN_EPS);

    f32x4 r;
    r[0] = (o0 - mu) * inv * sGamma[c0]     + sBeta[c0];
    r[1] = (o1 - mu) * inv * sGamma[c0 + 1] + sBeta[c0 + 1];
    r[2] = (o2 - mu) * inv * sGamma[c0 + 2] + sBeta[c0 + 2];
    r[3] = (o3 - mu) * inv * sGamma[c0 + 3] + sBeta[c0 + 3];
    // SINGLE-VARIABLE CHANGE vs round 8 (64us): non-temporal store.
    // out is 100MB/dispatch, never re-read; WRITE_SIZE proves every byte
    // reaches HBM regardless — plain stores only ALLOCATE dead lines in
    // L3, evicting the q/v lines that currently give ~50% read hits.
    __builtin_nontemporal_store(r, (f32x4*)(out + base));
}

extern "C" void kernel_launch(void* const* d_in, const int* in_sizes, int n_in,
                              void* d_out, int out_size, void* d_ws, size_t ws_size,
                              hipStream_t stream) {
    const float* query = (const float*)d_in[0];
    const float* value = (const float*)d_in[1];
    const float* Ww    = (const float*)d_in[2];
    const float* bw    = (const float*)d_in[3];
    const float* gamma = (const float*)d_in[4];
    const float* beta  = (const float*)d_in[5];
    float* outp = (float*)d_out;

    dydwconv_ln_kernel<<<BLOCKS, 256, 0, stream>>>(
        query, value, Ww, bw, gamma, beta, outp);
}